// Round 1
// baseline (334.073 us; speedup 1.0000x reference)
//
#include <hip/hip_runtime.h>

#define DIMN 64
#define LN 63
#define HIDN 64
#define BATCHN 16384

__device__ __forceinline__ float fast_exp(float v) {
    // e^v = 2^(v*log2(e)); v_exp_f32 is ~1 ulp
    return __builtin_amdgcn_exp2f(v * 1.4426950408889634f);
}

__device__ __forceinline__ float fast_tanh(float v) {
    // tanh(v) = 1 - 2/(e^{2v}+1); saturates correctly for |v| large
    float e = __builtin_amdgcn_exp2f(v * 2.8853900817779268f); // e^{2v}
    return 1.0f - 2.0f * __builtin_amdgcn_rcpf(e + 1.0f);
}

// One block = (row-tile of 256 rows) x (one autoregressive position l).
// Fuses layer1(masked matvec)+tanh -> layer2(64x64)+tanh -> layer3(64x2),
// then writes z column (reversed) directly and alpha to workspace.
__global__ __launch_bounds__(256, 2) void maf_main_kernel(
    const float* __restrict__ x,
    const float* __restrict__ W1, const float* __restrict__ b1,
    const float* __restrict__ W2, const float* __restrict__ b2,
    const float* __restrict__ W3, const float* __restrict__ b3,
    float* __restrict__ z_out,     // [BATCH][64], already in reversed order
    float* __restrict__ alpha_ws)  // [BATCH][63]
{
    __shared__ float w1s[64][64];  // masked: row j zeroed for j>l (row 63 always 0)
    __shared__ float w2s[64][64];
    __shared__ float w3s[64][2];
    __shared__ float b1s[64];
    __shared__ float b2s[64];
    __shared__ float b3s[2];

    const int tid = threadIdx.x;
    const int bid = blockIdx.x;
    const int l = bid % LN;        // 0..62, block-uniform
    const int rowTile = bid / LN;  // 0..63
    const int row = rowTile * 256 + tid;

    // ---- stage weights for this l into LDS (mask applied to W1) ----
    for (int i = tid; i < 64 * 64; i += 256) {
        const int j = i >> 6, h = i & 63;
        w1s[j][h] = (j <= l) ? W1[(l * LN + j) * HIDN + h] : 0.0f;
        w2s[j][h] = W2[(l * HIDN + j) * HIDN + h];
    }
    if (tid < 128) {
        w3s[tid >> 1][tid & 1] = W3[(l * HIDN + (tid >> 1)) * 2 + (tid & 1)];
    }
    if (tid < 64) {
        b1s[tid] = b1[l * HIDN + tid];
        b2s[tid] = b2[l * HIDN + tid];
    }
    if (tid < 2) b3s[tid] = b3[l * 2 + tid];
    __syncthreads();

    // ---- x row into registers (all static indices; fully unrolled) ----
    float xr[64];
    #pragma unroll
    for (int c = 0; c < 16; ++c) {
        const float4 v = *reinterpret_cast<const float4*>(&x[row * DIMN + c * 4]);
        xr[c * 4 + 0] = v.x; xr[c * 4 + 1] = v.y;
        xr[c * 4 + 2] = v.z; xr[c * 4 + 3] = v.w;
    }
    // NOTE: loaded separately (NOT xr[l+1]) to avoid runtime register indexing -> scratch
    const float xnext = x[row * DIMN + (l + 1)];

    // ---- layer 1: acc[h] = b1[h] + sum_{j<=l} xr[j] * W1m[j][h] ----
    float acc[64];
    #pragma unroll
    for (int h = 0; h < 64; ++h) acc[h] = b1s[h];

    #pragma unroll
    for (int j = 0; j < 64; ++j) {
        if (j > l) break;  // wave-uniform (l is block-uniform): cheap s_cbranch
        const float xv = xr[j];
        #pragma unroll
        for (int hc = 0; hc < 16; ++hc) {
            const float4 w = *reinterpret_cast<const float4*>(&w1s[j][hc * 4]);  // LDS broadcast
            acc[hc * 4 + 0] = fmaf(xv, w.x, acc[hc * 4 + 0]);
            acc[hc * 4 + 1] = fmaf(xv, w.y, acc[hc * 4 + 1]);
            acc[hc * 4 + 2] = fmaf(xv, w.z, acc[hc * 4 + 2]);
            acc[hc * 4 + 3] = fmaf(xv, w.w, acc[hc * 4 + 3]);
        }
    }

    float h1v[64];
    #pragma unroll
    for (int h = 0; h < 64; ++h) h1v[h] = fast_tanh(acc[h]);

    // ---- layer 2: acc2[k] = b2[k] + sum_h h1[h] * W2[h][k] ----
    float acc2[64];
    #pragma unroll
    for (int h = 0; h < 64; ++h) acc2[h] = b2s[h];

    #pragma unroll
    for (int j = 0; j < 64; ++j) {
        const float hv = h1v[j];
        #pragma unroll
        for (int hc = 0; hc < 16; ++hc) {
            const float4 w = *reinterpret_cast<const float4*>(&w2s[j][hc * 4]);
            acc2[hc * 4 + 0] = fmaf(hv, w.x, acc2[hc * 4 + 0]);
            acc2[hc * 4 + 1] = fmaf(hv, w.y, acc2[hc * 4 + 1]);
            acc2[hc * 4 + 2] = fmaf(hv, w.z, acc2[hc * 4 + 2]);
            acc2[hc * 4 + 3] = fmaf(hv, w.w, acc2[hc * 4 + 3]);
        }
    }

    // ---- layer 3 fused with tanh(h2): out = h2 . W3[:, 0:2] + b3 ----
    float o0 = b3s[0], o1 = b3s[1];
    #pragma unroll
    for (int h = 0; h < 64; ++h) {
        const float h2 = fast_tanh(acc2[h]);
        const float2 w = *reinterpret_cast<const float2*>(&w3s[h][0]);
        o0 = fmaf(h2, w.x, o0);  // mu contribution (column l+1)
        o1 = fmaf(h2, w.y, o1);  // alpha contribution (column l+1)
    }

    // z column c = l+1, stored reversed at 63-c
    const float zv = (xnext - o0) * fast_exp(-o1);
    z_out[row * DIMN + (DIMN - 1 - (l + 1))] = zv;
    alpha_ws[row * LN + l] = o1;
}

// Handles column 0 (initial_param) and the log_det reduction over alpha.
__global__ __launch_bounds__(256) void maf_finish_kernel(
    const float* __restrict__ x,
    const float* __restrict__ ip,
    const float* __restrict__ alpha_ws,
    float* __restrict__ z_out,
    float* __restrict__ ld_out)
{
    const int row = blockIdx.x * 256 + threadIdx.x;
    const float mu0 = ip[0];
    const float a0  = ip[1];
    float s = a0;
    #pragma unroll 7
    for (int i = 0; i < LN; ++i) s += alpha_ws[row * LN + i];
    z_out[row * DIMN + (DIMN - 1)] = (x[row * DIMN + 0] - mu0) * fast_exp(-a0);
    ld_out[row] = -s;
}

extern "C" void kernel_launch(void* const* d_in, const int* in_sizes, int n_in,
                              void* d_out, int out_size, void* d_ws, size_t ws_size,
                              hipStream_t stream) {
    const float* x  = (const float*)d_in[0];
    const float* ip = (const float*)d_in[1];
    const float* W1 = (const float*)d_in[2];
    const float* b1 = (const float*)d_in[3];
    const float* W2 = (const float*)d_in[4];
    const float* b2 = (const float*)d_in[5];
    const float* W3 = (const float*)d_in[6];
    const float* b3 = (const float*)d_in[7];

    float* z_out  = (float*)d_out;                       // [16384][64] reversed z
    float* ld_out = z_out + (size_t)BATCHN * DIMN;       // [16384] log_det
    float* alpha_ws = (float*)d_ws;                      // [16384][63], 4.1 MB

    maf_main_kernel<<<dim3(64 * LN), dim3(256), 0, stream>>>(
        x, W1, b1, W2, b2, W3, b3, z_out, alpha_ws);
    maf_finish_kernel<<<dim3(BATCHN / 256), dim3(256), 0, stream>>>(
        x, ip, alpha_ws, z_out, ld_out);
}

// Round 2
// 308.936 us; speedup vs baseline: 1.0814x; 1.0814x over previous
//
#include <hip/hip_runtime.h>

#define DIMN 64
#define LN 63
#define HIDN 64
#define BATCHN 16384

__device__ __forceinline__ float fast_exp(float v) {
    return __builtin_amdgcn_exp2f(v * 1.4426950408889634f);
}

__device__ __forceinline__ float fast_tanh(float v) {
    // tanh(v) = 1 - 2/(e^{2v}+1); saturates correctly for |v| large
    float e = __builtin_amdgcn_exp2f(v * 2.8853900817779268f); // e^{2v}
    return 1.0f - 2.0f * __builtin_amdgcn_rcpf(e + 1.0f);
}

// One block = (row-tile of 256 rows) x (one autoregressive position l).
// Fully-fused 3-layer MLP. ALL register-array indices are compile-time
// constants (no breaks, no runtime bounds) -> no scratch.
// Mask is folded into the LDS copy of W1 (rows j>l zeroed), so layer 1
// runs a dense, statically-unrolled 64-iteration loop.
__global__ __launch_bounds__(256, 2) void maf_main_kernel(
    const float* __restrict__ x,
    const float* __restrict__ W1, const float* __restrict__ b1,
    const float* __restrict__ W2, const float* __restrict__ b2,
    const float* __restrict__ W3, const float* __restrict__ b3,
    float* __restrict__ z_out,     // [BATCH][64], reversed order
    float* __restrict__ alpha_ws)  // [LN][BATCH]  (transposed: coalesced)
{
    __shared__ float w1s[64][64];  // masked: row j zeroed for j>l (row 63 always 0)
    __shared__ float w2s[64][64];
    __shared__ float w3s[64][2];
    __shared__ float b1s[64];
    __shared__ float b2s[64];
    __shared__ float b3s[2];

    const int tid = threadIdx.x;
    const int bid = blockIdx.x;
    const int l = bid % LN;        // 0..62, block-uniform
    const int rowTile = bid / LN;  // 0..63
    const int row = rowTile * 256 + tid;

    // ---- stage weights for this l into LDS (mask applied to W1) ----
    for (int i = tid; i < 64 * 64; i += 256) {
        const int j = i >> 6, h = i & 63;
        w1s[j][h] = (j <= l) ? W1[(l * LN + j) * HIDN + h] : 0.0f;
        w2s[j][h] = W2[(l * HIDN + j) * HIDN + h];
    }
    if (tid < 128) {
        w3s[tid >> 1][tid & 1] = W3[(l * HIDN + (tid >> 1)) * 2 + (tid & 1)];
    }
    if (tid < 64) {
        b1s[tid] = b1[l * HIDN + tid];
        b2s[tid] = b2[l * HIDN + tid];
    }
    if (tid < 2) b3s[tid] = b3[l * 2 + tid];
    __syncthreads();

    // ---- x row into registers (all static indices; fully unrolled) ----
    float xr[64];
    #pragma unroll
    for (int c = 0; c < 16; ++c) {
        const float4 v = *reinterpret_cast<const float4*>(&x[row * DIMN + c * 4]);
        xr[c * 4 + 0] = v.x; xr[c * 4 + 1] = v.y;
        xr[c * 4 + 2] = v.z; xr[c * 4 + 3] = v.w;
    }
    // loaded separately (NOT xr[l+1]): avoids runtime register indexing
    const float xnext = x[row * DIMN + (l + 1)];

    // ---- layer 1: acc[h] = b1[h] + sum_j xr[j] * W1masked[j][h] ----
    // Dense 64 iterations, fully unrolled: j>l terms are zero via mask.
    float acc[64];
    #pragma unroll
    for (int h = 0; h < 64; ++h) acc[h] = b1s[h];

    #pragma unroll
    for (int j = 0; j < 64; ++j) {
        const float xv = xr[j];
        #pragma unroll
        for (int hc = 0; hc < 16; ++hc) {
            const float4 w = *reinterpret_cast<const float4*>(&w1s[j][hc * 4]);  // LDS broadcast
            acc[hc * 4 + 0] = fmaf(xv, w.x, acc[hc * 4 + 0]);
            acc[hc * 4 + 1] = fmaf(xv, w.y, acc[hc * 4 + 1]);
            acc[hc * 4 + 2] = fmaf(xv, w.z, acc[hc * 4 + 2]);
            acc[hc * 4 + 3] = fmaf(xv, w.w, acc[hc * 4 + 3]);
        }
    }

    // tanh in place: xr dead after this point, acc becomes h1
    #pragma unroll
    for (int h = 0; h < 64; ++h) acc[h] = fast_tanh(acc[h]);

    // ---- layer 2: acc2[k] = b2[k] + sum_h h1[h] * W2[h][k] ----
    float acc2[64];
    #pragma unroll
    for (int h = 0; h < 64; ++h) acc2[h] = b2s[h];

    #pragma unroll
    for (int j = 0; j < 64; ++j) {
        const float hv = acc[j];
        #pragma unroll
        for (int hc = 0; hc < 16; ++hc) {
            const float4 w = *reinterpret_cast<const float4*>(&w2s[j][hc * 4]);
            acc2[hc * 4 + 0] = fmaf(hv, w.x, acc2[hc * 4 + 0]);
            acc2[hc * 4 + 1] = fmaf(hv, w.y, acc2[hc * 4 + 1]);
            acc2[hc * 4 + 2] = fmaf(hv, w.z, acc2[hc * 4 + 2]);
            acc2[hc * 4 + 3] = fmaf(hv, w.w, acc2[hc * 4 + 3]);
        }
    }

    // ---- layer 3 fused with tanh(h2): out = h2 . W3[:, 0:2] + b3 ----
    float o0 = b3s[0], o1 = b3s[1];
    #pragma unroll
    for (int h = 0; h < 64; ++h) {
        const float h2 = fast_tanh(acc2[h]);
        const float2 w = *reinterpret_cast<const float2*>(&w3s[h][0]);
        o0 = fmaf(h2, w.x, o0);  // mu  (column l+1)
        o1 = fmaf(h2, w.y, o1);  // alpha (column l+1)
    }

    // z column c = l+1, stored reversed at 63-c
    const float zv = (xnext - o0) * fast_exp(-o1);
    z_out[row * DIMN + (DIMN - 1 - (l + 1))] = zv;
    alpha_ws[l * BATCHN + row] = o1;   // transposed: lane-coalesced store
}

// Handles column 0 (initial_param) and the log_det reduction over alpha.
__global__ __launch_bounds__(256) void maf_finish_kernel(
    const float* __restrict__ x,
    const float* __restrict__ ip,
    const float* __restrict__ alpha_ws,  // [LN][BATCH]
    float* __restrict__ z_out,
    float* __restrict__ ld_out)
{
    const int row = blockIdx.x * 256 + threadIdx.x;
    const float mu0 = ip[0];
    const float a0  = ip[1];
    float s = a0;
    #pragma unroll 7
    for (int i = 0; i < LN; ++i) s += alpha_ws[i * BATCHN + row];  // coalesced
    z_out[row * DIMN + (DIMN - 1)] = (x[row * DIMN + 0] - mu0) * fast_exp(-a0);
    ld_out[row] = -s;
}

extern "C" void kernel_launch(void* const* d_in, const int* in_sizes, int n_in,
                              void* d_out, int out_size, void* d_ws, size_t ws_size,
                              hipStream_t stream) {
    const float* x  = (const float*)d_in[0];
    const float* ip = (const float*)d_in[1];
    const float* W1 = (const float*)d_in[2];
    const float* b1 = (const float*)d_in[3];
    const float* W2 = (const float*)d_in[4];
    const float* b2 = (const float*)d_in[5];
    const float* W3 = (const float*)d_in[6];
    const float* b3 = (const float*)d_in[7];

    float* z_out  = (float*)d_out;                       // [16384][64] reversed z
    float* ld_out = z_out + (size_t)BATCHN * DIMN;       // [16384] log_det
    float* alpha_ws = (float*)d_ws;                      // [63][16384], 4.1 MB

    maf_main_kernel<<<dim3(64 * LN), dim3(256), 0, stream>>>(
        x, W1, b1, W2, b2, W3, b3, z_out, alpha_ws);
    maf_finish_kernel<<<dim3(BATCHN / 256), dim3(256), 0, stream>>>(
        x, ip, alpha_ws, z_out, ld_out);
}

// Round 3
// 89.825 us; speedup vs baseline: 3.7192x; 3.4393x over previous
//
#include <hip/hip_runtime.h>

#define LN 63
#define BATCHN 16384

typedef __attribute__((ext_vector_type(8))) short bf16x8;   // 8 bf16 in 4 VGPRs
typedef __attribute__((ext_vector_type(4))) float f32x4;

__device__ __forceinline__ float fast_exp(float v) {
    return __builtin_amdgcn_exp2f(v * 1.4426950408889634f);
}
__device__ __forceinline__ float fast_tanh(float v) {
    float e = __builtin_amdgcn_exp2f(v * 2.8853900817779268f); // e^{2v}
    return 1.0f - 2.0f * __builtin_amdgcn_rcpf(e + 1.0f);
}
__device__ __forceinline__ short f2bf(float f) {
    __bf16 h = (__bf16)f;
    return __builtin_bit_cast(short, h);
}
__device__ __forceinline__ unsigned int pk2(float a, float b) {
    return (unsigned int)(unsigned short)f2bf(a) |
           ((unsigned int)(unsigned short)f2bf(b) << 16);
}

// Block = one l (0..62) x 256 batch rows. 4 waves; wave handles 4 groups of 16 rows.
// Swapped-operand MFMA chain: C1' = W1m^T . X^T  -> per-lane col = batch row.
// Layer2/3 consume C' directly as B-fragments via K-slot permutation kappa
// (folded into the LDS staging of W2^T / W3^T) -> no inter-layer transpose.
__global__ __launch_bounds__(256, 2) void maf_main_kernel(
    const float* __restrict__ x,
    const float* __restrict__ W1, const float* __restrict__ b1,
    const float* __restrict__ W2, const float* __restrict__ b2,
    const float* __restrict__ W3, const float* __restrict__ b3,
    float* __restrict__ zT,   // ws: [63][BATCH]  row cr=62-l  (z col l+1, reversed idx)
    float* __restrict__ aT)   // ws: [63][BATCH]  alpha col l+1
{
    // LDS rows of 128B (64 bf16): rows 0-63 = W1m^T (natural k), 64-127 = W2^T
    // (kappa-permuted k), 128-143 = W3^T padded to 16 rows (kappa-permuted k).
    // XOR swizzle: byte_in_row ^= (row&7)<<4  -> 2-way bank aliasing (free).
    __shared__ __align__(16) char wlds[144 * 128];

    const int t = threadIdx.x;
    const int bid = blockIdx.x;
    const int l = bid % LN;                 // block-uniform
    const int rowBase = (bid / LN) * 256;

    // ---------------- stage weights into LDS ----------------
    {
        const int h = t >> 2, jg = t & 3;   // h: output index of W^T row; jg: 16-wide j group
        const int sW = jg >> 1, ehi = jg & 1;
        const int swz = (h & 7) << 4;
        #pragma unroll
        for (int p = 0; p < 4; ++p) {
            float v0, v1, v2, v3;
            // W1 masked (j<=l), natural k order: byte = 2*j
            {
                const int j0 = 16 * jg + 4 * p;
                v0 = (j0 + 0 <= l) ? W1[(l * LN + j0 + 0) * 64 + h] : 0.0f;
                v1 = (j0 + 1 <= l) ? W1[(l * LN + j0 + 1) * 64 + h] : 0.0f;
                v2 = (j0 + 2 <= l) ? W1[(l * LN + j0 + 2) * 64 + h] : 0.0f;
                v3 = (j0 + 3 <= l) ? W1[(l * LN + j0 + 3) * 64 + h] : 0.0f;
                *reinterpret_cast<uint2*>(wlds + h * 128 + ((32 * jg + 8 * p) ^ swz)) =
                    make_uint2(pk2(v0, v1), pk2(v2, v3));
            }
            // W2, kappa-permuted: j=16jg+4p+q -> byte = 64*(jg>>1)+16*p+8*(jg&1)+2*q
            {
                const int j0 = 16 * jg + 4 * p;
                v0 = W2[(l * 64 + j0 + 0) * 64 + h];
                v1 = W2[(l * 64 + j0 + 1) * 64 + h];
                v2 = W2[(l * 64 + j0 + 2) * 64 + h];
                v3 = W2[(l * 64 + j0 + 3) * 64 + h];
                *reinterpret_cast<uint2*>(wlds + (64 + h) * 128 +
                                          ((64 * sW + 16 * p + 8 * ehi) ^ swz)) =
                    make_uint2(pk2(v0, v1), pk2(v2, v3));
            }
        }
    }
    // W3^T pad rows 2..15 with zeros (zeros are swizzle-invariant)
    if (t < 224) {
        *reinterpret_cast<uint2*>(wlds + (130 + (t >> 4)) * 128 + (t & 15) * 8) =
            make_uint2(0u, 0u);
    }
    // W3^T rows 0 (mu weights), 1 (alpha weights), kappa-permuted
    if (t < 128) {
        const int r = t >> 6, j = t & 63;
        const float v = W3[(l * 64 + j) * 2 + r];
        const int gj = (j >> 2) & 3, qj = j & 3, sj = j >> 5, ej = (j >> 4) & 1;
        *reinterpret_cast<unsigned short*>(
            wlds + (128 + r) * 128 +
            ((64 * sj + 16 * gj + 8 * ej + 2 * qj) ^ ((r & 7) << 4))) =
            (unsigned short)f2bf(v);
    }
    __syncthreads();

    const int lane = t & 63;
    const int w = t >> 6;
    const int g = lane >> 4;
    const int mcol = lane & 15;

    // ---------------- hoisted A-fragments (W^T) + biases ----------------
    bf16x8 w1f[2][4], w2f[2][4], w3f[2];
    #pragma unroll
    for (int s = 0; s < 2; ++s) {
        const int kb = 64 * s + 16 * g;
        #pragma unroll
        for (int tt = 0; tt < 4; ++tt) {
            const int r1 = tt * 16 + mcol;
            const int r2 = 64 + tt * 16 + mcol;
            w1f[s][tt] = *reinterpret_cast<const bf16x8*>(wlds + r1 * 128 + (kb ^ ((r1 & 7) << 4)));
            w2f[s][tt] = *reinterpret_cast<const bf16x8*>(wlds + r2 * 128 + (kb ^ ((r2 & 7) << 4)));
        }
        const int r3 = 128 + mcol;
        w3f[s] = *reinterpret_cast<const bf16x8*>(wlds + r3 * 128 + (kb ^ ((r3 & 7) << 4)));
    }
    f32x4 bias1[4], bias2[4];
    #pragma unroll
    for (int tt = 0; tt < 4; ++tt) {
        const float4 v1 = *reinterpret_cast<const float4*>(&b1[l * 64 + 16 * tt + 4 * g]);
        const float4 v2 = *reinterpret_cast<const float4*>(&b2[l * 64 + 16 * tt + 4 * g]);
        bias1[tt] = f32x4{v1.x, v1.y, v1.z, v1.w};
        bias2[tt] = f32x4{v2.x, v2.y, v2.z, v2.w};
    }
    const float b30 = b3[l * 2 + 0];
    const float b31 = b3[l * 2 + 1];

    // ---------------- 4 groups of 16 rows per wave ----------------
    #pragma unroll
    for (int grp = 0; grp < 4; ++grp) {
        const int row = rowBase + w * 64 + grp * 16 + mcol;
        const float* xr = x + (size_t)row * 64;

        // B-frag of layer1: x[row][32s+8g .. +8] (natural k), f32->bf16 in regs
        bf16x8 xf[2];
        #pragma unroll
        for (int s = 0; s < 2; ++s) {
            const float4 a = *reinterpret_cast<const float4*>(xr + 32 * s + 8 * g);
            const float4 b = *reinterpret_cast<const float4*>(xr + 32 * s + 8 * g + 4);
            bf16x8 f;
            f[0] = f2bf(a.x); f[1] = f2bf(a.y); f[2] = f2bf(a.z); f[3] = f2bf(a.w);
            f[4] = f2bf(b.x); f[5] = f2bf(b.y); f[6] = f2bf(b.z); f[7] = f2bf(b.w);
            xf[s] = f;
        }

        // layer 1: C1'[h1][m], bias-seeded accumulators
        f32x4 c1[4];
        #pragma unroll
        for (int tt = 0; tt < 4; ++tt) c1[tt] = bias1[tt];
        #pragma unroll
        for (int s = 0; s < 2; ++s)
            #pragma unroll
            for (int tt = 0; tt < 4; ++tt)
                c1[tt] = __builtin_amdgcn_mfma_f32_16x16x32_bf16(w1f[s][tt], xf[s], c1[tt], 0, 0, 0);

        // tanh + pack: kstep-s B-frag = tiles {2s, 2s+1}  (kappa ordering)
        bf16x8 pf[2];
        #pragma unroll
        for (int s = 0; s < 2; ++s) {
            bf16x8 f;
            #pragma unroll
            for (int q = 0; q < 4; ++q) {
                f[q]     = f2bf(fast_tanh(c1[2 * s][q]));
                f[4 + q] = f2bf(fast_tanh(c1[2 * s + 1][q]));
            }
            pf[s] = f;
        }

        // layer 2
        f32x4 c2[4];
        #pragma unroll
        for (int tt = 0; tt < 4; ++tt) c2[tt] = bias2[tt];
        #pragma unroll
        for (int s = 0; s < 2; ++s)
            #pragma unroll
            for (int tt = 0; tt < 4; ++tt)
                c2[tt] = __builtin_amdgcn_mfma_f32_16x16x32_bf16(w2f[s][tt], pf[s], c2[tt], 0, 0, 0);

        bf16x8 qf[2];
        #pragma unroll
        for (int s = 0; s < 2; ++s) {
            bf16x8 f;
            #pragma unroll
            for (int q = 0; q < 4; ++q) {
                f[q]     = f2bf(fast_tanh(c2[2 * s][q]));
                f[4 + q] = f2bf(fast_tanh(c2[2 * s + 1][q]));
            }
            qf[s] = f;
        }

        // layer 3: C3'[{mu,alpha}][m]
        f32x4 c3 = {0.0f, 0.0f, 0.0f, 0.0f};
        c3 = __builtin_amdgcn_mfma_f32_16x16x32_bf16(w3f[0], qf[0], c3, 0, 0, 0);
        c3 = __builtin_amdgcn_mfma_f32_16x16x32_bf16(w3f[1], qf[1], c3, 0, 0, 0);

        // epilogue: lanes g==0 hold row0=mu, row1=alpha for col m
        if (g == 0) {
            const float mu = c3[0] + b30;
            const float al = c3[1] + b31;
            const float xn = x[(size_t)row * 64 + l + 1];   // f32 precision input
            const float zv = (xn - mu) * fast_exp(-al);
            zT[(62 - l) * BATCHN + row] = zv;   // coalesced over m
            aT[l * BATCHN + row] = al;
        }
    }
}

// Fused: log_det reduction + z col 0 + LDS transpose zT -> coalesced z_out rows.
__global__ __launch_bounds__(256) void maf_finish_kernel(
    const float* __restrict__ x,
    const float* __restrict__ ip,
    const float* __restrict__ ws,
    float* __restrict__ z_out,
    float* __restrict__ ld_out)
{
    const float* zT = ws;
    const float* aT = ws + (size_t)LN * BATCHN;
    __shared__ float tile[64][129];   // +1 pad: conflict-free transposed reads

    const int t = threadIdx.x;
    const int rb = blockIdx.x * 256;
    const float mu0 = ip[0];
    const float a0  = ip[1];
    const float e0  = fast_exp(-a0);

    // log_det for this block's 256 rows (coalesced reads)
    {
        const int row = rb + t;
        float s = a0;
        for (int i = 0; i < LN; ++i) s += aT[i * BATCHN + row];
        ld_out[row] = -s;
    }

    // transpose 2 half-tiles of 128 rows x 64 cols
    #pragma unroll
    for (int hh = 0; hh < 2; ++hh) {
        const int RB = rb + hh * 128;
        const int r = t & 127;
        const int cb = t >> 7;   // 0: even cols, 1: odd cols
        #pragma unroll 8
        for (int k = 0; k < 32; ++k) {
            const int c = 2 * k + cb;
            float v;
            if (c < 63) v = zT[(size_t)c * BATCHN + RB + r];
            else        v = (x[(size_t)(RB + r) * 64] - mu0) * e0;  // z col 0 -> cr 63
            tile[c][r] = v;
        }
        __syncthreads();
        const int lane = t & 63;
        const int wv = t >> 6;
        #pragma unroll 8
        for (int i = 0; i < 32; ++i) {
            const int rr = wv * 32 + i;
            z_out[(size_t)(RB + rr) * 64 + lane] = tile[lane][rr];
        }
        __syncthreads();
    }
}

extern "C" void kernel_launch(void* const* d_in, const int* in_sizes, int n_in,
                              void* d_out, int out_size, void* d_ws, size_t ws_size,
                              hipStream_t stream) {
    const float* x  = (const float*)d_in[0];
    const float* ip = (const float*)d_in[1];
    const float* W1 = (const float*)d_in[2];
    const float* b1 = (const float*)d_in[3];
    const float* W2 = (const float*)d_in[4];
    const float* b2 = (const float*)d_in[5];
    const float* W3 = (const float*)d_in[6];
    const float* b3 = (const float*)d_in[7];

    float* z_out  = (float*)d_out;                     // [16384][64] (reversed cols)
    float* ld_out = z_out + (size_t)BATCHN * 64;       // [16384]
    float* zT = (float*)d_ws;                          // [63][16384]
    float* aT = zT + (size_t)LN * BATCHN;              // [63][16384]  (8.06 MB total)

    maf_main_kernel<<<dim3(LN * 64), dim3(256), 0, stream>>>(
        x, W1, b1, W2, b2, W3, b3, zT, aT);
    maf_finish_kernel<<<dim3(BATCHN / 256), dim3(256), 0, stream>>>(
        x, ip, (const float*)d_ws, z_out, ld_out);
}

// Round 4
// 79.201 us; speedup vs baseline: 4.2180x; 1.1341x over previous
//
#include <hip/hip_runtime.h>

#define LN 63
#define BATCHN 16384

typedef __attribute__((ext_vector_type(8))) short bf16x8;   // 8 bf16 in 4 VGPRs
typedef __attribute__((ext_vector_type(4))) float f32x4;

__device__ __forceinline__ float fast_exp(float v) {
    return __builtin_amdgcn_exp2f(v * 1.4426950408889634f);
}
__device__ __forceinline__ float fast_tanh(float v) {
    float e = __builtin_amdgcn_exp2f(v * 2.8853900817779268f); // e^{2v}
    return 1.0f - 2.0f * __builtin_amdgcn_rcpf(e + 1.0f);
}
__device__ __forceinline__ short f2bf(float f) {
    __bf16 h = (__bf16)f;
    return __builtin_bit_cast(short, h);
}
__device__ __forceinline__ unsigned int pk2(float a, float b) {
    return (unsigned int)(unsigned short)f2bf(a) |
           ((unsigned int)(unsigned short)f2bf(b) << 16);
}

// x (f32, [B][64]) -> xbf (bf16, [B][64]), elementwise. 1M elements.
__global__ __launch_bounds__(256) void x_cvt_kernel(
    const float* __restrict__ x, unsigned short* __restrict__ xbf)
{
    const int i = (blockIdx.x * 256 + threadIdx.x) * 4;
    const float4 v = *reinterpret_cast<const float4*>(x + i);
    ushort4 o;
    o.x = (unsigned short)f2bf(v.x);
    o.y = (unsigned short)f2bf(v.y);
    o.z = (unsigned short)f2bf(v.z);
    o.w = (unsigned short)f2bf(v.w);
    *reinterpret_cast<ushort4*>(xbf + i) = o;
}

// Block = one l (0..62) x 1024 batch rows (16 row-tiles). 4 waves; each wave
// processes 16 groups of 16 rows. Swapped-operand MFMA chain with kappa
// K-permutation folded into LDS staging (verified R2: absmax 0.0625).
template<int XBF>
__global__ __launch_bounds__(256, 4) void maf_main_kernel(
    const float* __restrict__ x,
    const unsigned short* __restrict__ xbf,
    const float* __restrict__ W1, const float* __restrict__ b1,
    const float* __restrict__ W2, const float* __restrict__ b2,
    const float* __restrict__ W3, const float* __restrict__ b3,
    float* __restrict__ zT,   // ws: [63][BATCH] row cr=62-l (z col l+1 reversed)
    float* __restrict__ aT)   // ws: [63][BATCH] alpha col l+1
{
    // rows 0-63: W1m^T (natural k); 64-127: W2^T (kappa k); 128-143: W3^T padded.
    // XOR swizzle: byte_in_row ^= (row&7)<<4.
    __shared__ __align__(16) char wlds[144 * 128];

    const int t = threadIdx.x;
    const int bid = blockIdx.x;
    const int l = bid % LN;                 // block-uniform
    const int rowBase = (bid / LN) * 1024;

    // ---------------- stage weights into LDS ----------------
    {
        const int h = t >> 2, jg = t & 3;
        const int sW = jg >> 1, ehi = jg & 1;
        const int swz = (h & 7) << 4;
        #pragma unroll
        for (int p = 0; p < 4; ++p) {
            float v0, v1, v2, v3;
            {   // W1 masked (j<=l), natural k: byte = 2*j
                const int j0 = 16 * jg + 4 * p;
                v0 = (j0 + 0 <= l) ? W1[(l * LN + j0 + 0) * 64 + h] : 0.0f;
                v1 = (j0 + 1 <= l) ? W1[(l * LN + j0 + 1) * 64 + h] : 0.0f;
                v2 = (j0 + 2 <= l) ? W1[(l * LN + j0 + 2) * 64 + h] : 0.0f;
                v3 = (j0 + 3 <= l) ? W1[(l * LN + j0 + 3) * 64 + h] : 0.0f;
                *reinterpret_cast<uint2*>(wlds + h * 128 + ((32 * jg + 8 * p) ^ swz)) =
                    make_uint2(pk2(v0, v1), pk2(v2, v3));
            }
            {   // W2, kappa-permuted: byte = 64*(jg>>1)+16*p+8*(jg&1)+2*q
                const int j0 = 16 * jg + 4 * p;
                v0 = W2[(l * 64 + j0 + 0) * 64 + h];
                v1 = W2[(l * 64 + j0 + 1) * 64 + h];
                v2 = W2[(l * 64 + j0 + 2) * 64 + h];
                v3 = W2[(l * 64 + j0 + 3) * 64 + h];
                *reinterpret_cast<uint2*>(wlds + (64 + h) * 128 +
                                          ((64 * sW + 16 * p + 8 * ehi) ^ swz)) =
                    make_uint2(pk2(v0, v1), pk2(v2, v3));
            }
        }
    }
    if (t < 224) {  // W3^T pad rows 2..15 with zeros
        *reinterpret_cast<uint2*>(wlds + (130 + (t >> 4)) * 128 + (t & 15) * 8) =
            make_uint2(0u, 0u);
    }
    if (t < 128) {  // W3^T rows 0 (mu), 1 (alpha), kappa-permuted
        const int r = t >> 6, j = t & 63;
        const float v = W3[(l * 64 + j) * 2 + r];
        const int gj = (j >> 2) & 3, qj = j & 3, sj = j >> 5, ej = (j >> 4) & 1;
        *reinterpret_cast<unsigned short*>(
            wlds + (128 + r) * 128 +
            ((64 * sj + 16 * gj + 8 * ej + 2 * qj) ^ ((r & 7) << 4))) =
            (unsigned short)f2bf(v);
    }
    __syncthreads();

    const int lane = t & 63;
    const int w = t >> 6;
    const int g = lane >> 4;
    const int mcol = lane & 15;

    // ---------------- A-fragments (W^T) + biases ----------------
    bf16x8 w1f[2][4], w2f[2][4], w3f[2];
    #pragma unroll
    for (int s = 0; s < 2; ++s) {
        const int kb = 64 * s + 16 * g;
        #pragma unroll
        for (int tt = 0; tt < 4; ++tt) {
            const int r1 = tt * 16 + mcol;
            const int r2 = 64 + tt * 16 + mcol;
            w1f[s][tt] = *reinterpret_cast<const bf16x8*>(wlds + r1 * 128 + (kb ^ ((r1 & 7) << 4)));
            w2f[s][tt] = *reinterpret_cast<const bf16x8*>(wlds + r2 * 128 + (kb ^ ((r2 & 7) << 4)));
        }
        const int r3 = 128 + mcol;
        w3f[s] = *reinterpret_cast<const bf16x8*>(wlds + r3 * 128 + (kb ^ ((r3 & 7) << 4)));
    }
    f32x4 bias1[4], bias2[4];
    #pragma unroll
    for (int tt = 0; tt < 4; ++tt) {
        const float4 v1 = *reinterpret_cast<const float4*>(&b1[l * 64 + 16 * tt + 4 * g]);
        const float4 v2 = *reinterpret_cast<const float4*>(&b2[l * 64 + 16 * tt + 4 * g]);
        bias1[tt] = f32x4{v1.x, v1.y, v1.z, v1.w};
        bias2[tt] = f32x4{v2.x, v2.y, v2.z, v2.w};
    }
    const float b30 = b3[l * 2 + 0];
    const float b31 = b3[l * 2 + 1];

    // ---------------- 16 groups of 16 rows per wave ----------------
    #pragma unroll 2
    for (int grp = 0; grp < 16; ++grp) {
        const int row = rowBase + w * 256 + grp * 16 + mcol;

        bf16x8 xf[2];
        if constexpr (XBF) {
            xf[0] = *reinterpret_cast<const bf16x8*>(xbf + (size_t)row * 64 + 8 * g);
            xf[1] = *reinterpret_cast<const bf16x8*>(xbf + (size_t)row * 64 + 32 + 8 * g);
        } else {
            const float* xr = x + (size_t)row * 64;
            #pragma unroll
            for (int s = 0; s < 2; ++s) {
                const float4 a = *reinterpret_cast<const float4*>(xr + 32 * s + 8 * g);
                const float4 b = *reinterpret_cast<const float4*>(xr + 32 * s + 8 * g + 4);
                bf16x8 f;
                f[0] = f2bf(a.x); f[1] = f2bf(a.y); f[2] = f2bf(a.z); f[3] = f2bf(a.w);
                f[4] = f2bf(b.x); f[5] = f2bf(b.y); f[6] = f2bf(b.z); f[7] = f2bf(b.w);
                xf[s] = f;
            }
        }

        // layer 1
        f32x4 c1[4];
        #pragma unroll
        for (int tt = 0; tt < 4; ++tt) c1[tt] = bias1[tt];
        #pragma unroll
        for (int s = 0; s < 2; ++s)
            #pragma unroll
            for (int tt = 0; tt < 4; ++tt)
                c1[tt] = __builtin_amdgcn_mfma_f32_16x16x32_bf16(w1f[s][tt], xf[s], c1[tt], 0, 0, 0);

        bf16x8 pf[2];
        #pragma unroll
        for (int s = 0; s < 2; ++s) {
            bf16x8 f;
            #pragma unroll
            for (int q = 0; q < 4; ++q) {
                f[q]     = f2bf(fast_tanh(c1[2 * s][q]));
                f[4 + q] = f2bf(fast_tanh(c1[2 * s + 1][q]));
            }
            pf[s] = f;
        }

        // layer 2
        f32x4 c2[4];
        #pragma unroll
        for (int tt = 0; tt < 4; ++tt) c2[tt] = bias2[tt];
        #pragma unroll
        for (int s = 0; s < 2; ++s)
            #pragma unroll
            for (int tt = 0; tt < 4; ++tt)
                c2[tt] = __builtin_amdgcn_mfma_f32_16x16x32_bf16(w2f[s][tt], pf[s], c2[tt], 0, 0, 0);

        bf16x8 qf[2];
        #pragma unroll
        for (int s = 0; s < 2; ++s) {
            bf16x8 f;
            #pragma unroll
            for (int q = 0; q < 4; ++q) {
                f[q]     = f2bf(fast_tanh(c2[2 * s][q]));
                f[4 + q] = f2bf(fast_tanh(c2[2 * s + 1][q]));
            }
            qf[s] = f;
        }

        // layer 3
        f32x4 c3 = {0.0f, 0.0f, 0.0f, 0.0f};
        c3 = __builtin_amdgcn_mfma_f32_16x16x32_bf16(w3f[0], qf[0], c3, 0, 0, 0);
        c3 = __builtin_amdgcn_mfma_f32_16x16x32_bf16(w3f[1], qf[1], c3, 0, 0, 0);

        if (g == 0) {
            const float mu = c3[0] + b30;
            const float al = c3[1] + b31;
            const float xn = x[(size_t)row * 64 + l + 1];   // f32 input
            const float zv = (xn - mu) * fast_exp(-al);
            zT[(62 - l) * BATCHN + row] = zv;
            aT[l * BATCHN + row] = al;
        }
    }
}

// 256 blocks x 64 rows: log_det + z col 0 + LDS transpose -> coalesced z_out.
__global__ __launch_bounds__(256) void maf_finish_kernel(
    const float* __restrict__ x,
    const float* __restrict__ ip,
    const float* __restrict__ ws,
    float* __restrict__ z_out,
    float* __restrict__ ld_out)
{
    const float* zT = ws;
    const float* aT = ws + (size_t)LN * BATCHN;
    __shared__ float tile[64][65];

    const int t = threadIdx.x;
    const int rb = blockIdx.x * 64;
    const float mu0 = ip[0];
    const float a0  = ip[1];
    const float e0  = fast_exp(-a0);

    // log_det: 4 lanes per row, shfl reduce
    {
        const int r = t >> 2, c = t & 3;
        const int row = rb + r;
        float s = 0.0f;
        for (int i = c; i < LN; i += 4) s += aT[(size_t)i * BATCHN + row];
        s += __shfl_xor(s, 1, 64);
        s += __shfl_xor(s, 2, 64);
        if (c == 0) ld_out[row] = -(s + a0);
    }

    // transpose 64 rows x 64 cols
    const int r = t & 63, cq = t >> 6;
    #pragma unroll
    for (int k = 0; k < 16; ++k) {
        const int c = cq * 16 + k;
        float v;
        if (c < 63) v = zT[(size_t)c * BATCHN + rb + r];
        else        v = (x[(size_t)(rb + r) * 64] - mu0) * e0;  // z col 0 -> cr 63
        tile[c][r] = v;
    }
    __syncthreads();
    #pragma unroll
    for (int i = 0; i < 16; ++i) {
        const int rr = cq * 16 + i;
        z_out[(size_t)(rb + rr) * 64 + r] = tile[r][rr];
    }
}

extern "C" void kernel_launch(void* const* d_in, const int* in_sizes, int n_in,
                              void* d_out, int out_size, void* d_ws, size_t ws_size,
                              hipStream_t stream) {
    const float* x  = (const float*)d_in[0];
    const float* ip = (const float*)d_in[1];
    const float* W1 = (const float*)d_in[2];
    const float* b1 = (const float*)d_in[3];
    const float* W2 = (const float*)d_in[4];
    const float* b2 = (const float*)d_in[5];
    const float* W3 = (const float*)d_in[6];
    const float* b3 = (const float*)d_in[7];

    float* z_out  = (float*)d_out;                     // [16384][64] (reversed cols)
    float* ld_out = z_out + (size_t)BATCHN * 64;       // [16384]
    float* zT = (float*)d_ws;                          // [63][16384]
    float* aT = zT + (size_t)LN * BATCHN;              // [63][16384]
    unsigned short* xbf = (unsigned short*)(aT + (size_t)LN * BATCHN);  // [16384][64] bf16

    const size_t need = (size_t)LN * BATCHN * 8 + (size_t)BATCHN * 64 * 2;
    if (ws_size >= need) {
        x_cvt_kernel<<<dim3(BATCHN * 64 / 1024), dim3(256), 0, stream>>>(x, xbf);
        maf_main_kernel<1><<<dim3(LN * 16), dim3(256), 0, stream>>>(
            x, xbf, W1, b1, W2, b2, W3, b3, zT, aT);
    } else {
        maf_main_kernel<0><<<dim3(LN * 16), dim3(256), 0, stream>>>(
            x, xbf, W1, b1, W2, b2, W3, b3, zT, aT);
    }
    maf_finish_kernel<<<dim3(BATCHN / 64), dim3(256), 0, stream>>>(
        x, ip, (const float*)d_ws, z_out, ld_out);
}